// Round 21
// baseline (791.506 us; speedup 1.0000x reference)
//
#include <hip/hip_runtime.h>
#include <hip/hip_bf16.h>
#include <math.h>

#define B_  64
#define S_  16
#define T_  48
#define E_  300
#define H_  150
#define G_  300   // 2H
#define NC_ 300
#define NW_ (B_*S_)     // 1024 word-level batch
#define RW_ (T_*NW_)    // 49152 word rows
#define RS_ (S_*B_)     // 1024 sentence rows
#define GST 960         // sentence gi row stride (floats)

typedef __attribute__((ext_vector_type(8))) short bf16x8;
typedef __attribute__((ext_vector_type(4))) float f32x4;

__device__ __forceinline__ float sigm(float x){ return 1.0f/(1.0f+__expf(-x)); }

__device__ __forceinline__ ushort f2bf_rne(float x){
  uint u = __float_as_uint(x);
  return (ushort)((u + 0x7FFFu + ((u>>16)&1u)) >> 16);
}

// ---------------------------------------------------------------------------
// Whh[2][450][150] -> Wblk[2][38][450][4], zero-padded (sentence gru v4)
// ---------------------------------------------------------------------------
__global__ __launch_bounds__(256) void prep_whh_kernel(
    const float* __restrict__ Whh, float* __restrict__ Wblk){
  int idx = blockIdx.x*256 + threadIdx.x;
  if (idx >= 2*38*450*4) return;
  int k  = idx & 3;
  int j  = (idx >> 2) % 450;
  int e4 = (idx >> 2) / 450 % 38;
  int d  = idx / (38*450*4);
  int e  = e4*4 + k;
  Wblk[idx] = (e < 150) ? Whh[((size_t)d*450 + j)*150 + e] : 0.f;
}

// ---------------------------------------------------------------------------
// Whh[2][450][150] -> Bs_hi/Bs_lo[2][512][160] bf16 (zero-padded, hi/lo split)
// ---------------------------------------------------------------------------
__global__ __launch_bounds__(256) void prep_whh_mfma(
    const float* __restrict__ Whh, ushort* __restrict__ Bsh,
    ushort* __restrict__ Bsl){
  int idx = blockIdx.x*256 + threadIdx.x;
  if (idx >= 2*512*160) return;
  int k = idx % 160;
  int j = (idx / 160) % 512;
  int d = idx / (512*160);
  float x = (j < 450 && k < 150) ? Whh[((size_t)d*450 + j)*150 + k] : 0.f;
  ushort hb = f2bf_rne(x);
  Bsh[idx] = hb;
  Bsl[idx] = f2bf_rne(x - __uint_as_float(((uint)hb)<<16));
}

// ---------------------------------------------------------------------------
// generic fp32 -> bf16 hi/lo split: W[R][C] -> Whi/Wlo[gridDim.x][Cp]
// ---------------------------------------------------------------------------
__global__ __launch_bounds__(128) void split_w_gen(
    const float* __restrict__ W, ushort* __restrict__ Whi,
    ushort* __restrict__ Wlo, int R, int C, int Cp){
  int j = blockIdx.x;
  for (int k = threadIdx.x; k < Cp; k += 128){
    float x = (j < R && k < C) ? W[(size_t)j*C + k] : 0.f;
    ushort hb = f2bf_rne(x);
    float hf = __uint_as_float(((uint)hb)<<16);
    Whi[(size_t)j*Cp + k] = hb;
    Wlo[(size_t)j*Cp + k] = f2bf_rne(x - hf);
  }
}

// ---------------------------------------------------------------------------
// gi via bf16x3 MFMA. v6: TILED output giT[t*16+nblk][nt57][row64][c16] —
// wave-contiguous 1KB stores per nt, no staging, 1 barrier/nt.
// ---------------------------------------------------------------------------
__global__ __launch_bounds__(256) void gi_mfma_v6(
    const int* __restrict__ docs, const float* __restrict__ emb,
    const ushort* __restrict__ Whi, const ushort* __restrict__ Wlo,
    const float* __restrict__ bih, float* __restrict__ giT){
  __shared__ __align__(16) ushort Bhi[2][16*328];
  __shared__ __align__(16) ushort Blo[2][16*328];
  __shared__ int toks[64];
  int tid = threadIdx.x;
  int gr0 = blockIdx.x * 64;
  int t  = gr0 >> 10;
  int n0 = gr0 & 1023;
  int nblk = n0 >> 6;
  if (tid < 64) toks[tid] = docs[(n0 + tid)*T_ + t];
  uint4 pb[5];
#pragma unroll
  for (int i=0;i<5;i++){
    int c = tid + i*256;
    int half = (c >= 640) ? 1 : 0; int cc = c - half*640;
    int row = cc/40, o16 = cc - row*40;
    const ushort* src = half ? Wlo : Whi;
    pb[i] = *(const uint4*)&src[(size_t)row*320 + o16*8];
  }
  __syncthreads();   // toks visible
  int w = tid >> 6, L = tid & 63;
  int lrow = L & 15, lseg = L >> 4;
  const float* aptr = emb + (size_t)toks[w*16 + lrow]*300;
  bf16x8 ah[10], al[10];
#pragma unroll
  for (int ks=0; ks<10; ks++){
    int k0 = ks*32 + lseg*8;
    float x[8];
    if (k0 + 8 <= 300){
      float4 v0 = *(const float4*)&aptr[k0];
      float4 v1 = *(const float4*)&aptr[k0+4];
      x[0]=v0.x; x[1]=v0.y; x[2]=v0.z; x[3]=v0.w;
      x[4]=v1.x; x[5]=v1.y; x[6]=v1.z; x[7]=v1.w;
    } else {
#pragma unroll
      for (int u=0;u<8;u++) x[u] = (k0+u < 300) ? aptr[k0+u] : 0.f;
    }
#pragma unroll
    for (int u=0;u<8;u++){
      ushort hb = f2bf_rne(x[u]);
      float lo = x[u] - __uint_as_float(((uint)hb)<<16);
      ah[ks][u] = (short)hb;
      al[ks][u] = (short)f2bf_rne(lo);
    }
  }
#pragma unroll
  for (int i=0;i<5;i++){
    int c = tid + i*256;
    int half = (c >= 640) ? 1 : 0; int cc = c - half*640;
    int row = cc/40, o16 = cc - row*40;
    ushort* dst = half ? Blo[0] : Bhi[0];
    *(uint4*)&dst[row*328 + o16*8] = pb[i];
  }
  __syncthreads();
  int buf = 0;
  int bfb = lrow*328 + lseg*8;
  float* tile0 = giT + ((size_t)(t*16 + nblk)*57)*1024
                     + (w*16 + lseg*4)*16 + lrow;
  for (int nt = 0; nt < 57; ++nt){
    if (nt < 56){
#pragma unroll
      for (int i=0;i<5;i++){
        int c = tid + i*256;
        int half = (c >= 640) ? 1 : 0; int cc = c - half*640;
        int row = cc/40, o16 = cc - row*40;
        const ushort* src = half ? Wlo : Whi;
        pb[i] = *(const uint4*)&src[(size_t)((nt+1)*16 + row)*320 + o16*8];
      }
    }
    f32x4 acc = {0.f, 0.f, 0.f, 0.f};
#pragma unroll
    for (int ks=0; ks<10; ks++){
      bf16x8 bh = *(const bf16x8*)&Bhi[buf][bfb + ks*32];
      bf16x8 bl = *(const bf16x8*)&Blo[buf][bfb + ks*32];
      acc = __builtin_amdgcn_mfma_f32_16x16x32_bf16(ah[ks], bh, acc, 0, 0, 0);
      acc = __builtin_amdgcn_mfma_f32_16x16x32_bf16(ah[ks], bl, acc, 0, 0, 0);
      acc = __builtin_amdgcn_mfma_f32_16x16x32_bf16(al[ks], bh, acc, 0, 0, 0);
    }
    {
      int col = nt*16 + lrow;
      float bb = (col < 900) ? bih[col] : 0.f;
      float* p = tile0 + (size_t)nt*1024;
#pragma unroll
      for (int r=0;r<4;r++) p[r*16] = acc[r] + bb;
    }
    if (nt < 56){
#pragma unroll
      for (int i=0;i<5;i++){
        int c = tid + i*256;
        int half = (c >= 640) ? 1 : 0; int cc = c - half*640;
        int row = cc/40, o16 = cc - row*40;
        ushort* dst = half ? Blo[buf^1] : Bhi[buf^1];
        *(uint4*)&dst[row*328 + o16*8] = pb[i];
      }
    }
    __syncthreads();
    buf ^= 1;
  }
}

// ---------------------------------------------------------------------------
// att score via bf16x3 MFMA (r14 dbuf version — known-good)
// ---------------------------------------------------------------------------
__global__ __launch_bounds__(256,3) void att_mfma_kernel(
    const float* __restrict__ hs, const ushort* __restrict__ Whi,
    const ushort* __restrict__ Wlo, const float* __restrict__ bias,
    const float* __restrict__ ctx, float* __restrict__ score, int Rtot){
  __shared__ __align__(16) ushort Bhi[2][16*328];
  __shared__ __align__(16) ushort Blo[2][16*328];
  int tid = threadIdx.x;
  int r0 = blockIdx.x * 64;
  uint4 pb[5];
#pragma unroll
  for (int i=0;i<5;i++){
    int c = tid + i*256;
    int half = (c >= 640) ? 1 : 0; int cc = c - half*640;
    int row = cc/40, o16 = cc - row*40;
    const ushort* src = half ? Wlo : Whi;
    pb[i] = *(const uint4*)&src[(size_t)row*320 + o16*8];
  }
  int w = tid >> 6, L = tid & 63;
  int lrow = L & 15, lseg = L >> 4;
  int arow = r0 + w*16 + lrow;
  bool avalid = arow < Rtot;
  const float* aptr = hs + (size_t)(avalid ? arow : 0)*300;
  bf16x8 ah[10], al[10];
#pragma unroll
  for (int ks=0; ks<10; ks++){
    int k0 = ks*32 + lseg*8;
    float x[8];
    if (avalid && k0 + 8 <= 300){
      float4 v0 = *(const float4*)&aptr[k0];
      float4 v1 = *(const float4*)&aptr[k0+4];
      x[0]=v0.x; x[1]=v0.y; x[2]=v0.z; x[3]=v0.w;
      x[4]=v1.x; x[5]=v1.y; x[6]=v1.z; x[7]=v1.w;
    } else {
#pragma unroll
      for (int u=0;u<8;u++) x[u] = (avalid && k0+u < 300) ? aptr[k0+u] : 0.f;
    }
#pragma unroll
    for (int u=0;u<8;u++){
      ushort hb = f2bf_rne(x[u]);
      float lo = x[u] - __uint_as_float(((uint)hb)<<16);
      ah[ks][u] = (short)hb;
      al[ks][u] = (short)f2bf_rne(lo);
    }
  }
#pragma unroll
  for (int i=0;i<5;i++){
    int c = tid + i*256;
    int half = (c >= 640) ? 1 : 0; int cc = c - half*640;
    int row = cc/40, o16 = cc - row*40;
    ushort* dst = half ? Blo[0] : Bhi[0];
    *(uint4*)&dst[row*328 + o16*8] = pb[i];
  }
  __syncthreads();
  int buf = 0;
  int bfb = lrow*328 + lseg*8;
  float part[4] = {0.f,0.f,0.f,0.f};
  for (int nt = 0; nt < 19; ++nt){
    if (nt < 18){
#pragma unroll
      for (int i=0;i<5;i++){
        int c = tid + i*256;
        int half = (c >= 640) ? 1 : 0; int cc = c - half*640;
        int row = cc/40, o16 = cc - row*40;
        const ushort* src = half ? Wlo : Whi;
        pb[i] = *(const uint4*)&src[(size_t)((nt+1)*16 + row)*320 + o16*8];
      }
    }
    f32x4 acc = {0.f, 0.f, 0.f, 0.f};
#pragma unroll
    for (int ks=0; ks<10; ks++){
      bf16x8 bh = *(const bf16x8*)&Bhi[buf][bfb + ks*32];
      bf16x8 bl = *(const bf16x8*)&Blo[buf][bfb + ks*32];
      acc = __builtin_amdgcn_mfma_f32_16x16x32_bf16(ah[ks], bh, acc, 0, 0, 0);
      acc = __builtin_amdgcn_mfma_f32_16x16x32_bf16(ah[ks], bl, acc, 0, 0, 0);
      acc = __builtin_amdgcn_mfma_f32_16x16x32_bf16(al[ks], bh, acc, 0, 0, 0);
    }
    int col = nt*16 + lrow;
    if (col < 300){
      float bb = bias[col], cx = ctx[col];
#pragma unroll
      for (int r=0;r<4;r++) part[r] += cx * tanhf(acc[r] + bb);
    }
    if (nt < 18){
#pragma unroll
      for (int i=0;i<5;i++){
        int c = tid + i*256;
        int half = (c >= 640) ? 1 : 0; int cc = c - half*640;
        int row = cc/40, o16 = cc - row*40;
        ushort* dst = half ? Blo[buf^1] : Bhi[buf^1];
        *(uint4*)&dst[row*328 + o16*8] = pb[i];
      }
    }
    __syncthreads();
    buf ^= 1;
  }
#pragma unroll
  for (int off=1; off<16; off<<=1){
#pragma unroll
    for (int r=0;r<4;r++) part[r] += __shfl_xor(part[r], off);
  }
  if (lrow == 0){
    int rbase = r0 + w*16 + lseg*4;
#pragma unroll
    for (int r=0;r<4;r++)
      if (rbase + r < Rtot) score[rbase + r] = part[r];
  }
}

// sentence-level gi (tiny: 64 blocks, fp32), row-major stride GST
__global__ __launch_bounds__(256) void sent_gi_kernel(
    const float* __restrict__ sv, const float* __restrict__ Wih,
    const float* __restrict__ bih, float* __restrict__ gi){
  __shared__ float A[16][G_];
  int r0 = blockIdx.x * 16;
  int s  = r0 >> 6;
  int bb_ = r0 & 63;
  for (int idx = threadIdx.x; idx < 16*75; idx += 256){
    int row = idx / 75, e4 = idx - row*75;
    *(float4*)&A[row][e4*4] =
        *(const float4*)&sv[(((size_t)(bb_+row))*S_ + s)*G_ + e4*4];
  }
  __syncthreads();
  int q = threadIdx.x;
  if (q >= 225) return;
  int j0 = q*4;
  const float4* w0 = (const float4*)(Wih + (size_t)(j0  )*G_);
  const float4* w1 = (const float4*)(Wih + (size_t)(j0+1)*G_);
  const float4* w2 = (const float4*)(Wih + (size_t)(j0+2)*G_);
  const float4* w3 = (const float4*)(Wih + (size_t)(j0+3)*G_);
  float acc[16][4];
#pragma unroll
  for (int i=0;i<16;i++){ acc[i][0]=0.f; acc[i][1]=0.f; acc[i][2]=0.f; acc[i][3]=0.f; }
  for (int e4=0; e4<75; e4++){
    float4 b0=w0[e4], b1=w1[e4], b2=w2[e4], b3=w3[e4];
#pragma unroll
    for (int i=0;i<16;i++){
      float4 av = *(const float4*)&A[i][e4*4];
      acc[i][0] += av.x*b0.x + av.y*b0.y + av.z*b0.z + av.w*b0.w;
      acc[i][1] += av.x*b1.x + av.y*b1.y + av.z*b1.z + av.w*b1.w;
      acc[i][2] += av.x*b2.x + av.y*b2.y + av.z*b2.z + av.w*b2.w;
      acc[i][3] += av.x*b3.x + av.y*b3.y + av.z*b3.z + av.w*b3.w;
    }
  }
  float4 bb = *(const float4*)&bih[j0];
#pragma unroll
  for (int i=0;i<16;i++){
    float4 o4;
    o4.x = acc[i][0]+bb.x; o4.y = acc[i][1]+bb.y;
    o4.z = acc[i][2]+bb.z; o4.w = acc[i][3]+bb.w;
    *(float4*)&gi[((size_t)(s*B_) + bb_ + i)*GST + j0] = o4;
  }
}

// ---------------------------------------------------------------------------
// GRU scan via MFMA (word), TILED gi reads. Occupancy pinned: volatile LDS
// pad (cannot be DCE'd -> 81KB static -> 1 block/CU at runtime) +
// amdgpu_waves_per_eu(2,2) (codegen VGPR budget 256 -> B fragments stay
// register-resident; r20 showed VGPR=128 + pad DCE'd = B re-streamed L2).
// ---------------------------------------------------------------------------
__global__ __attribute__((amdgpu_waves_per_eu(2,2)))
__launch_bounds__(512) void gru_mfma2(
    const float* __restrict__ giT, const ushort* __restrict__ Bsh,
    const ushort* __restrict__ Bsl, const float* __restrict__ bhh,
    float* __restrict__ hs, int T, int N){
  __shared__ __align__(16) ushort Ahi[16*168];
  __shared__ __align__(16) ushort Alo[16*168];
  __shared__ float gh[16*468];
  __shared__ float lds_pad[10240];   // occupancy limiter: forces 1 block/CU
  int tid = threadIdx.x;
  int d  = blockIdx.y;
  int n0 = blockIdx.x * 8;
  int nblk = n0 >> 6, rowbase = n0 & 63;
  if (N == -12345){                   // never true; volatile store survives DCE
    volatile float* vp = lds_pad;
    vp[tid] = 0.f;
  }
  for (int i = tid; i < 16*168; i += 512){ Ahi[i] = 0; Alo[i] = 0; }
  int wv = tid >> 6, L = tid & 63;
  int lrow = L & 15, lseg = L >> 4;
  bf16x8 Bh[4][5], Bl[4][5];
  {
    const ushort* bh_ = Bsh + (size_t)d*512*160;
    const ushort* bl_ = Bsl + (size_t)d*512*160;
#pragma unroll
    for (int q=0;q<4;q++){
      int row = (wv + q*8)*16 + lrow;
#pragma unroll
      for (int ks=0;ks<5;ks++){
        Bh[q][ks] = *(const bf16x8*)&bh_[(size_t)row*160 + lseg*8 + ks*32];
        Bl[q][ks] = *(const bf16x8*)&bl_[(size_t)row*160 + lseg*8 + ks*32];
      }
    }
  }
  int erow[3], eh[3];
  float bb_r[3], bb_z[3], bb_n[3], hold[3];
  size_t offr[3], offz[3], offn[3];
#pragma unroll
  for (int r=0;r<3;r++){
    int e = tid + r*512;
    bool v = e < 1200;
    int e2 = v ? e : 0;
    erow[r] = e2 / 150; eh[r] = e2 % 150;
    bb_r[r] = v ? bhh[d*450 + eh[r]]        : 0.f;
    bb_z[r] = v ? bhh[d*450 + 150 + eh[r]]  : 0.f;
    bb_n[r] = v ? bhh[d*450 + 300 + eh[r]]  : 0.f;
    hold[r] = 0.f;
    int cr = d*450 + eh[r];
    int cz = d*450 + 150 + eh[r];
    int cn = d*450 + 300 + eh[r];
    int rw = rowbase + erow[r];
    offr[r] = (size_t)(cr>>4)*1024 + rw*16 + (cr&15);
    offz[r] = (size_t)(cz>>4)*1024 + rw*16 + (cz&15);
    offn[r] = (size_t)(cn>>4)*1024 + rw*16 + (cn&15);
  }
  __syncthreads();
  for (int step = 0; step < T; ++step){
    int t = d ? (T-1-step) : step;
    bf16x8 Ah[5], Al[5];
#pragma unroll
    for (int ks=0;ks<5;ks++){
      Ah[ks] = *(const bf16x8*)&Ahi[lrow*168 + lseg*8 + ks*32];
      Al[ks] = *(const bf16x8*)&Alo[lrow*168 + lseg*8 + ks*32];
    }
#pragma unroll
    for (int q=0;q<4;q++){
      int nt = wv + q*8;
      if (nt < 29){
        f32x4 acc = {0.f,0.f,0.f,0.f};
#pragma unroll
        for (int ks=0;ks<5;ks++){
          acc = __builtin_amdgcn_mfma_f32_16x16x32_bf16(Ah[ks], Bh[q][ks], acc, 0,0,0);
          acc = __builtin_amdgcn_mfma_f32_16x16x32_bf16(Ah[ks], Bl[q][ks], acc, 0,0,0);
          acc = __builtin_amdgcn_mfma_f32_16x16x32_bf16(Al[ks], Bh[q][ks], acc, 0,0,0);
        }
        int col = nt*16 + lrow;
#pragma unroll
        for (int r=0;r<4;r++)
          gh[(lseg*4 + r)*468 + col] = acc[r];
      }
    }
    const float* base = giT + ((size_t)(t*16 + nblk)*57)*1024;
    float pr[3], pz[3], pn[3];
#pragma unroll
    for (int r=0;r<3;r++){
      if (tid + r*512 < 1200){
        pr[r] = base[offr[r]];
        pz[r] = base[offz[r]];
        pn[r] = base[offn[r]];
      }
    }
    __syncthreads();
#pragma unroll
    for (int r=0;r<3;r++){
      if (tid + r*512 < 1200){
        int row = erow[r], h = eh[r];
        float ghr = gh[row*468 + h];
        float ghz = gh[row*468 + 150 + h];
        float ghn = gh[row*468 + 300 + h];
        float rr = sigm(pr[r] + ghr + bb_r[r]);
        float zz = sigm(pz[r] + ghz + bb_z[r]);
        float nn = tanhf(pn[r] + rr*(ghn + bb_n[r]));
        float h2 = (1.f - zz)*nn + zz*hold[r];
        hold[r] = h2;
        ushort hb = f2bf_rne(h2);
        Ahi[row*168 + h] = hb;
        Alo[row*168 + h] = f2bf_rne(h2 - __uint_as_float(((uint)hb)<<16));
        hs[((size_t)t*N + n0 + row)*G_ + d*H_ + h] = h2;
      }
    }
    __syncthreads();
  }
}

// ---------------------------------------------------------------------------
// GRU scan v4 (sentence, tiny): row-major gi stride GST
// ---------------------------------------------------------------------------
template<int R>
__global__ __launch_bounds__(512,2) void gru_scan_v4(
    const float* __restrict__ gi, const float* __restrict__ Wblk,
    const float* __restrict__ bhh, float* __restrict__ hs,
    int T, int N){
  int d  = blockIdx.y;
  int n0 = blockIdx.x * R;
  __shared__ float hl[2][R][152];
  __shared__ float gh[R][452];
  int tid = threadIdx.x;
  for (int idx = tid; idx < 2*R*152; idx += 512) (&hl[0][0][0])[idx] = 0.f;
  bool jact = tid < 450;
  bool hact = tid < 150;
  float4 Wr[38];
  float bj = 0.f;
  {
    const float4* Wb4 = (const float4*)(Wblk + (size_t)d*38*1800);
    int jj = jact ? tid : 0;
#pragma unroll
    for (int e4 = 0; e4 < 38; ++e4) Wr[e4] = Wb4[e4*450 + jj];
    if (jact) bj = bhh[d*450 + tid];
  }
  float hreg[R];
#pragma unroll
  for (int i=0;i<R;i++) hreg[i] = 0.f;
  int buf = 0;
  __syncthreads();
  for (int step = 0; step < T; ++step){
    int t = d ? (T-1-step) : step;
    const float* gib = gi + ((size_t)t*N + n0)*GST + d*450;
    float pre[R][3];
    if (hact){
#pragma unroll
      for (int i=0;i<R;i++){
        pre[i][0] = gib[(size_t)i*GST + tid];
        pre[i][1] = gib[(size_t)i*GST + 150 + tid];
        pre[i][2] = gib[(size_t)i*GST + 300 + tid];
      }
    }
    if (jact){
      float acc[R];
#pragma unroll
      for (int i=0;i<R;i++) acc[i] = 0.f;
#pragma unroll
      for (int e4 = 0; e4 < 38; ++e4){
        float4 w = Wr[e4];
#pragma unroll
        for (int i=0;i<R;i++){
          float4 hv = *(const float4*)&hl[buf][i][e4*4];
          acc[i] += w.x*hv.x + w.y*hv.y + w.z*hv.z + w.w*hv.w;
        }
      }
#pragma unroll
      for (int i=0;i<R;i++) gh[i][tid] = acc[i] + bj;
    }
    __syncthreads();
    if (hact){
#pragma unroll
      for (int i=0;i<R;i++){
        float r  = sigm(pre[i][0] + gh[i][tid]);
        float z  = sigm(pre[i][1] + gh[i][150+tid]);
        float nn = tanhf(pre[i][2] + r*gh[i][300+tid]);
        float h2 = (1.f - z)*nn + z*hreg[i];
        hreg[i] = h2;
        hl[buf^1][i][tid] = h2;
        hs[((size_t)t*N + n0 + i)*G_ + d*H_ + tid] = h2;
      }
    }
    buf ^= 1;
    __syncthreads();
  }
}

// softmax over t (per n) + weighted sum
__global__ __launch_bounds__(256) void att_combine_kernel(
    const float* __restrict__ score, const float* __restrict__ hs,
    float* __restrict__ out, int T, int N){
  int n = blockIdx.x;
  __shared__ float wa[64];
  if (threadIdx.x < T) wa[threadIdx.x] = score[threadIdx.x*N + n];
  __syncthreads();
  float m = -1e30f;
  for (int t=0;t<T;t++) m = fmaxf(m, wa[t]);
  float den = 0.f;
  for (int t=0;t<T;t++) den += __expf(wa[t]-m);
  float inv = 1.f/den;
  __syncthreads();
  if (threadIdx.x < T) wa[threadIdx.x] = __expf(wa[threadIdx.x]-m)*inv;
  __syncthreads();
  for (int g = threadIdx.x; g < G_; g += 256){
    float acc = 0.f;
    for (int t=0;t<T;t++) acc += wa[t] * hs[((size_t)t*N+n)*G_ + g];
    out[(size_t)n*G_ + g] = acc;
  }
}

// one wave per (b,k): both cosine sims
__global__ __launch_bounds__(256) void cossim_kernel(
    const int* __restrict__ cand, const int* __restrict__ sens,
    const float* __restrict__ ent, const float* __restrict__ sv,
    const float* __restrict__ odoc, float* __restrict__ sim){
  int w = (blockIdx.x*256 + threadIdx.x) >> 6;
  int lane = threadIdx.x & 63;
  if (w >= B_*NC_) return;
  int b = w / NC_, k = w - b*NC_;
  const float* c  = ent + (size_t)cand[b*NC_ + k]*E_;
  const float* a1 = sv  + ((size_t)b*S_ + sens[b])*G_;
  const float* a2 = odoc + (size_t)b*G_;
  float d1=0.f,d2=0.f,cc=0.f,n1=0.f,n2=0.f;
  for (int e = lane; e < E_; e += 64){
    float cv=c[e], v1=a1[e], v2=a2[e];
    d1+=v1*cv; d2+=v2*cv; cc+=cv*cv; n1+=v1*v1; n2+=v2*v2;
  }
  for (int off=32; off; off>>=1){
    d1+=__shfl_xor(d1,off); d2+=__shfl_xor(d2,off); cc+=__shfl_xor(cc,off);
    n1+=__shfl_xor(n1,off); n2+=__shfl_xor(n2,off);
  }
  if (lane == 0){
    float nc = sqrtf(cc);
    sim[(size_t)b*600 + k]       = d1 / fmaxf(sqrtf(n1)*nc, 1e-8f);
    sim[(size_t)b*600 + 300 + k] = d2 / fmaxf(sqrtf(n2)*nc, 1e-8f);
  }
}

// score = sim @ linW^T + linb; gold gather; argmax (first-max tie rule)
__global__ __launch_bounds__(256) void final_kernel(
    const float* __restrict__ sim, const float* __restrict__ linW,
    const float* __restrict__ linb, const int* __restrict__ idx,
    float* __restrict__ out){
  int b = blockIdx.x;
  __shared__ float ss[600];
  __shared__ float sc[300];
  __shared__ float bv[256];
  __shared__ int   bi[256];
  for (int j = threadIdx.x; j < 600; j += 256) ss[j] = sim[(size_t)b*600 + j];
  __syncthreads();
  float bestv = -1e30f; int besti = 0;
  for (int i = threadIdx.x; i < 300; i += 256){
    const float4* wr = (const float4*)(linW + (size_t)i*600);
    float acc = linb[i];
    for (int j4=0; j4<150; j4++){
      float4 w = wr[j4];
      int j = j4*4;
      acc += w.x*ss[j] + w.y*ss[j+1] + w.z*ss[j+2] + w.w*ss[j+3];
    }
    sc[i] = acc;
    out[64 + (size_t)b*300 + i] = acc;
    if (acc > bestv){ bestv = acc; besti = i; }
  }
  bv[threadIdx.x] = bestv; bi[threadIdx.x] = besti;
  __syncthreads();
  for (int s=128; s; s>>=1){
    if (threadIdx.x < s){
      float ov = bv[threadIdx.x+s]; int oi = bi[threadIdx.x+s];
      if (ov > bv[threadIdx.x] || (ov == bv[threadIdx.x] && oi < bi[threadIdx.x])){
        bv[threadIdx.x] = ov; bi[threadIdx.x] = oi;
      }
    }
    __syncthreads();
  }
  if (threadIdx.x == 0){
    out[b] = sc[idx[b]-1];
    out[64 + 64*300 + b] = (float)bi[0];
  }
}

extern "C" void kernel_launch(void* const* d_in, const int* in_sizes, int n_in,
                              void* d_out, int out_size, void* d_ws, size_t ws_size,
                              hipStream_t stream){
  const int*   docs  = (const int*)d_in[0];
  const int*   sens  = (const int*)d_in[1];
  const int*   cand  = (const int*)d_in[2];
  const int*   idx   = (const int*)d_in[3];
  const float* wemb  = (const float*)d_in[4];
  const float* eemb  = (const float*)d_in[5];
  const float* Wih_w = (const float*)d_in[6];
  const float* Whh_w = (const float*)d_in[7];
  const float* bih_w = (const float*)d_in[8];
  const float* bhh_w = (const float*)d_in[9];
  const float* attW_w= (const float*)d_in[10];
  const float* attb_w= (const float*)d_in[11];
  const float* ctx_w = (const float*)d_in[12];
  const float* Wih_s = (const float*)d_in[13];
  const float* Whh_s = (const float*)d_in[14];
  const float* bih_s = (const float*)d_in[15];
  const float* bhh_s = (const float*)d_in[16];
  const float* attW_s= (const float*)d_in[17];
  const float* attb_s= (const float*)d_in[18];
  const float* ctx_s = (const float*)d_in[19];
  const float* linW  = (const float*)d_in[20];
  const float* linb  = (const float*)d_in[21];

  float* ws = (float*)d_ws;
  size_t off = 0;
  float* gi_w    = ws + off; off += (size_t)T_*16*57*1024;  // tiled giT, 179 MB
  float* hs_w    = ws + off; off += (size_t)T_*NW_*G_;      // 59 MB
  float* score_w = ws + off; off += (size_t)T_*NW_;
  float* sv      = ws + off; off += (size_t)NW_*G_;
  float* hs_s    = ws + off; off += (size_t)S_*B_*G_;
  float* score_s = ws + off; off += (size_t)S_*B_;
  float* odoc    = ws + off; off += (size_t)B_*G_;
  float* sim     = ws + off; off += (size_t)B_*600;
  float* Wblk_s  = ws + off; off += (size_t)2*38*450*4;     // sentence Whh tiles
  ushort* Whi    = (ushort*)(ws + off); off += (size_t)912*320/2;
  ushort* Wlo    = (ushort*)(ws + off); off += (size_t)912*320/2;
  ushort* WAhi   = (ushort*)(ws + off); off += (size_t)304*320/2;
  ushort* WAlo   = (ushort*)(ws + off); off += (size_t)304*320/2;
  ushort* WShi   = (ushort*)(ws + off); off += (size_t)304*320/2;
  ushort* WSlo   = (ushort*)(ws + off); off += (size_t)304*320/2;
  ushort* Bsh    = (ushort*)(ws + off); off += (size_t)2*512*160/2;  // gru B hi
  ushort* Bsl    = (ushort*)(ws + off); off += (size_t)2*512*160/2;  // gru B lo
  float* gi_s    = gi_w;   // aliases giT: word gi dead before sent_gi runs

  float* out = (float*)d_out;

  // one-time weight preps
  prep_whh_kernel<<<(2*38*450*4+255)/256, 256, 0, stream>>>(Whh_s, Wblk_s);
  prep_whh_mfma<<<(2*512*160+255)/256, 256, 0, stream>>>(Whh_w, Bsh, Bsl);
  split_w_gen<<<912, 128, 0, stream>>>(Wih_w, Whi, Wlo, 900, 300, 320);
  split_w_gen<<<304, 128, 0, stream>>>(attW_w, WAhi, WAlo, 300, 300, 320);
  split_w_gen<<<304, 128, 0, stream>>>(attW_s, WShi, WSlo, 300, 300, 320);

  // word level
  gi_mfma_v6<<<RW_/64, 256, 0, stream>>>(docs, wemb, Whi, Wlo, bih_w, gi_w);
  gru_mfma2<<<dim3(NW_/8, 2), 512, 0, stream>>>(gi_w, Bsh, Bsl, bhh_w,
                                                hs_w, T_, NW_);
  att_mfma_kernel<<<RW_/64, 256, 0, stream>>>(hs_w, WAhi, WAlo, attb_w,
                                              ctx_w, score_w, RW_);
  att_combine_kernel<<<NW_, 256, 0, stream>>>(score_w, hs_w, sv, T_, NW_);

  // sentence level
  sent_gi_kernel<<<RS_/16, 256, 0, stream>>>(sv, Wih_s, bih_s, gi_s);
  gru_scan_v4<2><<<dim3(B_/2, 2), 512, 0, stream>>>(gi_s, Wblk_s, bhh_s,
                                                    hs_s, S_, B_);
  att_mfma_kernel<<<RS_/64, 256, 0, stream>>>(hs_s, WShi, WSlo, attb_s,
                                              ctx_s, score_s, RS_);
  att_combine_kernel<<<B_, 256, 0, stream>>>(score_s, hs_s, odoc, S_, B_);

  // similarity + linear + gold + argmax
  cossim_kernel<<<(B_*NC_*64)/256, 256, 0, stream>>>(cand, sens, eemb, sv, odoc, sim);
  final_kernel<<<B_, 256, 0, stream>>>(sim, linW, linb, idx, out);
}

// Round 22
// 680.059 us; speedup vs baseline: 1.1639x; 1.1639x over previous
//
#include <hip/hip_runtime.h>
#include <hip/hip_bf16.h>
#include <math.h>

#define B_  64
#define S_  16
#define T_  48
#define E_  300
#define H_  150
#define G_  300   // 2H
#define NC_ 300
#define NW_ (B_*S_)     // 1024 word-level batch
#define RW_ (T_*NW_)    // 49152 word rows
#define RS_ (S_*B_)     // 1024 sentence rows
#define GST 960         // gi row stride (floats): 3840 B aligned rows

typedef __attribute__((ext_vector_type(8))) short bf16x8;
typedef __attribute__((ext_vector_type(4))) float f32x4;

__device__ __forceinline__ float sigm(float x){ return 1.0f/(1.0f+__expf(-x)); }

__device__ __forceinline__ ushort f2bf_rne(float x){
  uint u = __float_as_uint(x);
  return (ushort)((u + 0x7FFFu + ((u>>16)&1u)) >> 16);
}

// ---------------------------------------------------------------------------
// Whh[2][450][150] -> Wblk[2][38][450][4], zero-padded (sentence gru v4)
// ---------------------------------------------------------------------------
__global__ __launch_bounds__(256) void prep_whh_kernel(
    const float* __restrict__ Whh, float* __restrict__ Wblk){
  int idx = blockIdx.x*256 + threadIdx.x;
  if (idx >= 2*38*450*4) return;
  int k  = idx & 3;
  int j  = (idx >> 2) % 450;
  int e4 = (idx >> 2) / 450 % 38;
  int d  = idx / (38*450*4);
  int e  = e4*4 + k;
  Wblk[idx] = (e < 150) ? Whh[((size_t)d*450 + j)*150 + e] : 0.f;
}

// ---------------------------------------------------------------------------
// Whh[2][450][150] -> Bs_hi/Bs_lo[2][512][160] bf16 (zero-padded, hi/lo split)
// ---------------------------------------------------------------------------
__global__ __launch_bounds__(256) void prep_whh_mfma(
    const float* __restrict__ Whh, ushort* __restrict__ Bsh,
    ushort* __restrict__ Bsl){
  int idx = blockIdx.x*256 + threadIdx.x;
  if (idx >= 2*512*160) return;
  int k = idx % 160;
  int j = (idx / 160) % 512;
  int d = idx / (512*160);
  float x = (j < 450 && k < 150) ? Whh[((size_t)d*450 + j)*150 + k] : 0.f;
  ushort hb = f2bf_rne(x);
  Bsh[idx] = hb;
  Bsl[idx] = f2bf_rne(x - __uint_as_float(((uint)hb)<<16));
}

// ---------------------------------------------------------------------------
// generic fp32 -> bf16 hi/lo split: W[R][C] -> Whi/Wlo[gridDim.x][Cp]
// ---------------------------------------------------------------------------
__global__ __launch_bounds__(128) void split_w_gen(
    const float* __restrict__ W, ushort* __restrict__ Whi,
    ushort* __restrict__ Wlo, int R, int C, int Cp){
  int j = blockIdx.x;
  for (int k = threadIdx.x; k < Cp; k += 128){
    float x = (j < R && k < C) ? W[(size_t)j*C + k] : 0.f;
    ushort hb = f2bf_rne(x);
    float hf = __uint_as_float(((uint)hb)<<16);
    Whi[(size_t)j*Cp + k] = hb;
    Wlo[(size_t)j*Cp + k] = f2bf_rne(x - hf);
  }
}

// ---------------------------------------------------------------------------
// gi = X @ Wih^T + bih via bf16x3 MFMA. v5 (measured best, r18: 218us):
// dbuf B in LDS, 2-nt Cst groups (51.5 KB total -> 2 blocks/CU), row-major
// gi at stride GST, 128B-aligned row chunks.
// ---------------------------------------------------------------------------
__global__ __launch_bounds__(256) void gi_mfma_v5(
    const int* __restrict__ docs, const float* __restrict__ emb,
    const ushort* __restrict__ Whi, const ushort* __restrict__ Wlo,
    const float* __restrict__ bih, float* __restrict__ gi){
  __shared__ __align__(16) ushort Bhi[2][16*328];
  __shared__ __align__(16) ushort Blo[2][16*328];
  __shared__ __align__(16) float  Cst[64*36];
  __shared__ int toks[64];
  int tid = threadIdx.x;
  int gr0 = blockIdx.x * 64;
  int t  = gr0 >> 10;
  int n0 = gr0 & 1023;
  if (tid < 64) toks[tid] = docs[(n0 + tid)*T_ + t];
  uint4 pb[5];
#pragma unroll
  for (int i=0;i<5;i++){
    int c = tid + i*256;
    int half = (c >= 640) ? 1 : 0; int cc = c - half*640;
    int row = cc/40, o16 = cc - row*40;
    const ushort* src = half ? Wlo : Whi;
    pb[i] = *(const uint4*)&src[(size_t)row*320 + o16*8];
  }
  __syncthreads();   // toks visible
  int w = tid >> 6, L = tid & 63;
  int lrow = L & 15, lseg = L >> 4;
  const float* aptr = emb + (size_t)toks[w*16 + lrow]*300;
  bf16x8 ah[10], al[10];
#pragma unroll
  for (int ks=0; ks<10; ks++){
    int k0 = ks*32 + lseg*8;
    float x[8];
    if (k0 + 8 <= 300){
      float4 v0 = *(const float4*)&aptr[k0];
      float4 v1 = *(const float4*)&aptr[k0+4];
      x[0]=v0.x; x[1]=v0.y; x[2]=v0.z; x[3]=v0.w;
      x[4]=v1.x; x[5]=v1.y; x[6]=v1.z; x[7]=v1.w;
    } else {
#pragma unroll
      for (int u=0;u<8;u++) x[u] = (k0+u < 300) ? aptr[k0+u] : 0.f;
    }
#pragma unroll
    for (int u=0;u<8;u++){
      ushort hb = f2bf_rne(x[u]);
      float lo = x[u] - __uint_as_float(((uint)hb)<<16);
      ah[ks][u] = (short)hb;
      al[ks][u] = (short)f2bf_rne(lo);
    }
  }
#pragma unroll
  for (int i=0;i<5;i++){
    int c = tid + i*256;
    int half = (c >= 640) ? 1 : 0; int cc = c - half*640;
    int row = cc/40, o16 = cc - row*40;
    ushort* dst = half ? Blo[0] : Bhi[0];
    *(uint4*)&dst[row*328 + o16*8] = pb[i];
  }
  __syncthreads();
  int buf = 0;
  int bfb = lrow*328 + lseg*8;
  int rl0 = w*16 + lseg*4;
  f32x4 acc2[2];
  for (int g2 = 0; g2 < 28; ++g2){
#pragma unroll
    for (int q = 0; q < 2; ++q){
      int nt = g2*2 + q;       // 0..55, nt+1 <= 56 valid
#pragma unroll
      for (int i=0;i<5;i++){
        int c = tid + i*256;
        int half = (c >= 640) ? 1 : 0; int cc = c - half*640;
        int row = cc/40, o16 = cc - row*40;
        const ushort* src = half ? Wlo : Whi;
        pb[i] = *(const uint4*)&src[(size_t)((nt+1)*16 + row)*320 + o16*8];
      }
      f32x4 acc = {0.f, 0.f, 0.f, 0.f};
#pragma unroll
      for (int ks=0; ks<10; ks++){
        bf16x8 bh = *(const bf16x8*)&Bhi[buf][bfb + ks*32];
        bf16x8 bl = *(const bf16x8*)&Blo[buf][bfb + ks*32];
        acc = __builtin_amdgcn_mfma_f32_16x16x32_bf16(ah[ks], bh, acc, 0, 0, 0);
        acc = __builtin_amdgcn_mfma_f32_16x16x32_bf16(ah[ks], bl, acc, 0, 0, 0);
        acc = __builtin_amdgcn_mfma_f32_16x16x32_bf16(al[ks], bh, acc, 0, 0, 0);
      }
      acc2[q] = acc;
#pragma unroll
      for (int i=0;i<5;i++){
        int c = tid + i*256;
        int half = (c >= 640) ? 1 : 0; int cc = c - half*640;
        int row = cc/40, o16 = cc - row*40;
        ushort* dst = half ? Blo[buf^1] : Bhi[buf^1];
        *(uint4*)&dst[row*328 + o16*8] = pb[i];
      }
      __syncthreads();
      buf ^= 1;
    }
#pragma unroll
    for (int q = 0; q < 2; ++q){
#pragma unroll
      for (int r = 0; r < 4; ++r)
        Cst[(rl0 + r)*36 + q*16 + lrow] = acc2[q][r];
    }
    __syncthreads();
#pragma unroll
    for (int i = 0; i < 2; ++i){
      int idxc = tid + i*256;
      int row = idxc >> 3, c2 = idxc & 7;
      int colb = g2*32 + c2*4;
      float4 v = *(float4*)&Cst[row*36 + c2*4];
      float4 bb = *(const float4*)&bih[colb];
      v.x += bb.x; v.y += bb.y; v.z += bb.z; v.w += bb.w;
      *(float4*)&gi[(size_t)(gr0 + row)*GST + colb] = v;
    }
  }
  // tail: nt = 56 (B56 already in LDS buf), cols 896..899 valid
  {
    f32x4 acc = {0.f, 0.f, 0.f, 0.f};
#pragma unroll
    for (int ks=0; ks<10; ks++){
      bf16x8 bh = *(const bf16x8*)&Bhi[buf][bfb + ks*32];
      bf16x8 bl = *(const bf16x8*)&Blo[buf][bfb + ks*32];
      acc = __builtin_amdgcn_mfma_f32_16x16x32_bf16(ah[ks], bh, acc, 0, 0, 0);
      acc = __builtin_amdgcn_mfma_f32_16x16x32_bf16(ah[ks], bl, acc, 0, 0, 0);
      acc = __builtin_amdgcn_mfma_f32_16x16x32_bf16(al[ks], bh, acc, 0, 0, 0);
    }
    int col = 896 + lrow;
    if (col < 900){
      float bb = bih[col];
#pragma unroll
      for (int r=0;r<4;r++)
        gi[(size_t)(gr0 + rl0 + r)*GST + col] = acc[r] + bb;
    }
  }
}

// ---------------------------------------------------------------------------
// att score via bf16x3 MFMA (dbuf, known-good)
// ---------------------------------------------------------------------------
__global__ __launch_bounds__(256,3) void att_mfma_kernel(
    const float* __restrict__ hs, const ushort* __restrict__ Whi,
    const ushort* __restrict__ Wlo, const float* __restrict__ bias,
    const float* __restrict__ ctx, float* __restrict__ score, int Rtot){
  __shared__ __align__(16) ushort Bhi[2][16*328];
  __shared__ __align__(16) ushort Blo[2][16*328];
  int tid = threadIdx.x;
  int r0 = blockIdx.x * 64;
  uint4 pb[5];
#pragma unroll
  for (int i=0;i<5;i++){
    int c = tid + i*256;
    int half = (c >= 640) ? 1 : 0; int cc = c - half*640;
    int row = cc/40, o16 = cc - row*40;
    const ushort* src = half ? Wlo : Whi;
    pb[i] = *(const uint4*)&src[(size_t)row*320 + o16*8];
  }
  int w = tid >> 6, L = tid & 63;
  int lrow = L & 15, lseg = L >> 4;
  int arow = r0 + w*16 + lrow;
  bool avalid = arow < Rtot;
  const float* aptr = hs + (size_t)(avalid ? arow : 0)*300;
  bf16x8 ah[10], al[10];
#pragma unroll
  for (int ks=0; ks<10; ks++){
    int k0 = ks*32 + lseg*8;
    float x[8];
    if (avalid && k0 + 8 <= 300){
      float4 v0 = *(const float4*)&aptr[k0];
      float4 v1 = *(const float4*)&aptr[k0+4];
      x[0]=v0.x; x[1]=v0.y; x[2]=v0.z; x[3]=v0.w;
      x[4]=v1.x; x[5]=v1.y; x[6]=v1.z; x[7]=v1.w;
    } else {
#pragma unroll
      for (int u=0;u<8;u++) x[u] = (avalid && k0+u < 300) ? aptr[k0+u] : 0.f;
    }
#pragma unroll
    for (int u=0;u<8;u++){
      ushort hb = f2bf_rne(x[u]);
      float lo = x[u] - __uint_as_float(((uint)hb)<<16);
      ah[ks][u] = (short)hb;
      al[ks][u] = (short)f2bf_rne(lo);
    }
  }
#pragma unroll
  for (int i=0;i<5;i++){
    int c = tid + i*256;
    int half = (c >= 640) ? 1 : 0; int cc = c - half*640;
    int row = cc/40, o16 = cc - row*40;
    ushort* dst = half ? Blo[0] : Bhi[0];
    *(uint4*)&dst[row*328 + o16*8] = pb[i];
  }
  __syncthreads();
  int buf = 0;
  int bfb = lrow*328 + lseg*8;
  float part[4] = {0.f,0.f,0.f,0.f};
  for (int nt = 0; nt < 19; ++nt){
    if (nt < 18){
#pragma unroll
      for (int i=0;i<5;i++){
        int c = tid + i*256;
        int half = (c >= 640) ? 1 : 0; int cc = c - half*640;
        int row = cc/40, o16 = cc - row*40;
        const ushort* src = half ? Wlo : Whi;
        pb[i] = *(const uint4*)&src[(size_t)((nt+1)*16 + row)*320 + o16*8];
      }
    }
    f32x4 acc = {0.f, 0.f, 0.f, 0.f};
#pragma unroll
    for (int ks=0; ks<10; ks++){
      bf16x8 bh = *(const bf16x8*)&Bhi[buf][bfb + ks*32];
      bf16x8 bl = *(const bf16x8*)&Blo[buf][bfb + ks*32];
      acc = __builtin_amdgcn_mfma_f32_16x16x32_bf16(ah[ks], bh, acc, 0, 0, 0);
      acc = __builtin_amdgcn_mfma_f32_16x16x32_bf16(ah[ks], bl, acc, 0, 0, 0);
      acc = __builtin_amdgcn_mfma_f32_16x16x32_bf16(al[ks], bh, acc, 0, 0, 0);
    }
    int col = nt*16 + lrow;
    if (col < 300){
      float bb = bias[col], cx = ctx[col];
#pragma unroll
      for (int r=0;r<4;r++) part[r] += cx * tanhf(acc[r] + bb);
    }
    if (nt < 18){
#pragma unroll
      for (int i=0;i<5;i++){
        int c = tid + i*256;
        int half = (c >= 640) ? 1 : 0; int cc = c - half*640;
        int row = cc/40, o16 = cc - row*40;
        ushort* dst = half ? Blo[buf^1] : Bhi[buf^1];
        *(uint4*)&dst[row*328 + o16*8] = pb[i];
      }
    }
    __syncthreads();
    buf ^= 1;
  }
#pragma unroll
  for (int off=1; off<16; off<<=1){
#pragma unroll
    for (int r=0;r<4;r++) part[r] += __shfl_xor(part[r], off);
  }
  if (lrow == 0){
    int rbase = r0 + w*16 + lseg*4;
#pragma unroll
    for (int r=0;r<4;r++)
      if (rbase + r < Rtot) score[rbase + r] = part[r];
  }
}

// sentence-level gi (tiny: 64 blocks, fp32), stride GST
__global__ __launch_bounds__(256) void sent_gi_kernel(
    const float* __restrict__ sv, const float* __restrict__ Wih,
    const float* __restrict__ bih, float* __restrict__ gi){
  __shared__ float A[16][G_];
  int r0 = blockIdx.x * 16;
  int s  = r0 >> 6;
  int bb_ = r0 & 63;
  for (int idx = threadIdx.x; idx < 16*75; idx += 256){
    int row = idx / 75, e4 = idx - row*75;
    *(float4*)&A[row][e4*4] =
        *(const float4*)&sv[(((size_t)(bb_+row))*S_ + s)*G_ + e4*4];
  }
  __syncthreads();
  int q = threadIdx.x;
  if (q >= 225) return;
  int j0 = q*4;
  const float4* w0 = (const float4*)(Wih + (size_t)(j0  )*G_);
  const float4* w1 = (const float4*)(Wih + (size_t)(j0+1)*G_);
  const float4* w2 = (const float4*)(Wih + (size_t)(j0+2)*G_);
  const float4* w3 = (const float4*)(Wih + (size_t)(j0+3)*G_);
  float acc[16][4];
#pragma unroll
  for (int i=0;i<16;i++){ acc[i][0]=0.f; acc[i][1]=0.f; acc[i][2]=0.f; acc[i][3]=0.f; }
  for (int e4=0; e4<75; e4++){
    float4 b0=w0[e4], b1=w1[e4], b2=w2[e4], b3=w3[e4];
#pragma unroll
    for (int i=0;i<16;i++){
      float4 av = *(const float4*)&A[i][e4*4];
      acc[i][0] += av.x*b0.x + av.y*b0.y + av.z*b0.z + av.w*b0.w;
      acc[i][1] += av.x*b1.x + av.y*b1.y + av.z*b1.z + av.w*b1.w;
      acc[i][2] += av.x*b2.x + av.y*b2.y + av.z*b2.z + av.w*b2.w;
      acc[i][3] += av.x*b3.x + av.y*b3.y + av.z*b3.z + av.w*b3.w;
    }
  }
  float4 bb = *(const float4*)&bih[j0];
#pragma unroll
  for (int i=0;i<16;i++){
    float4 o4;
    o4.x = acc[i][0]+bb.x; o4.y = acc[i][1]+bb.y;
    o4.z = acc[i][2]+bb.z; o4.w = acc[i][3]+bb.w;
    *(float4*)&gi[((size_t)(s*B_) + bb_ + i)*GST + j0] = o4;
  }
}

// ---------------------------------------------------------------------------
// GRU scan via MFMA (word level), row-major GST gi reads (r17/r18 config)
// ---------------------------------------------------------------------------
__global__ __launch_bounds__(512,2) void gru_mfma2(
    const float* __restrict__ gi, const ushort* __restrict__ Bsh,
    const ushort* __restrict__ Bsl, const float* __restrict__ bhh,
    float* __restrict__ hs, int T, int N){
  __shared__ __align__(16) ushort Ahi[16*168];
  __shared__ __align__(16) ushort Alo[16*168];
  __shared__ float gh[16*468];
  int tid = threadIdx.x;
  int d  = blockIdx.y;
  int n0 = blockIdx.x * 8;
  for (int i = tid; i < 16*168; i += 512){ Ahi[i] = 0; Alo[i] = 0; }
  int wv = tid >> 6, L = tid & 63;
  int lrow = L & 15, lseg = L >> 4;
  bf16x8 Bh[4][5], Bl[4][5];
  {
    const ushort* bh_ = Bsh + (size_t)d*512*160;
    const ushort* bl_ = Bsl + (size_t)d*512*160;
#pragma unroll
    for (int q=0;q<4;q++){
      int row = (wv + q*8)*16 + lrow;
#pragma unroll
      for (int ks=0;ks<5;ks++){
        Bh[q][ks] = *(const bf16x8*)&bh_[(size_t)row*160 + lseg*8 + ks*32];
        Bl[q][ks] = *(const bf16x8*)&bl_[(size_t)row*160 + lseg*8 + ks*32];
      }
    }
  }
  int erow[3], eh[3];
  float bb_r[3], bb_z[3], bb_n[3], hold[3];
#pragma unroll
  for (int r=0;r<3;r++){
    int e = tid + r*512;
    bool v = e < 1200;
    int e2 = v ? e : 0;
    erow[r] = e2 / 150; eh[r] = e2 % 150;
    bb_r[r] = v ? bhh[d*450 + eh[r]]        : 0.f;
    bb_z[r] = v ? bhh[d*450 + 150 + eh[r]]  : 0.f;
    bb_n[r] = v ? bhh[d*450 + 300 + eh[r]]  : 0.f;
    hold[r] = 0.f;
  }
  __syncthreads();
  for (int step = 0; step < T; ++step){
    int t = d ? (T-1-step) : step;
    bf16x8 Ah[5], Al[5];
#pragma unroll
    for (int ks=0;ks<5;ks++){
      Ah[ks] = *(const bf16x8*)&Ahi[lrow*168 + lseg*8 + ks*32];
      Al[ks] = *(const bf16x8*)&Alo[lrow*168 + lseg*8 + ks*32];
    }
#pragma unroll
    for (int q=0;q<4;q++){
      int nt = wv + q*8;
      if (nt < 29){
        f32x4 acc = {0.f,0.f,0.f,0.f};
#pragma unroll
        for (int ks=0;ks<5;ks++){
          acc = __builtin_amdgcn_mfma_f32_16x16x32_bf16(Ah[ks], Bh[q][ks], acc, 0,0,0);
          acc = __builtin_amdgcn_mfma_f32_16x16x32_bf16(Ah[ks], Bl[q][ks], acc, 0,0,0);
          acc = __builtin_amdgcn_mfma_f32_16x16x32_bf16(Al[ks], Bh[q][ks], acc, 0,0,0);
        }
        int col = nt*16 + lrow;
#pragma unroll
        for (int r=0;r<4;r++)
          gh[(lseg*4 + r)*468 + col] = acc[r];
      }
    }
    const float* gib = gi + ((size_t)t*N + n0)*GST + d*450;
    float pr[3], pz[3], pn[3];
#pragma unroll
    for (int r=0;r<3;r++){
      if (tid + r*512 < 1200){
        const float* g0 = gib + (size_t)erow[r]*GST + eh[r];
        pr[r] = g0[0]; pz[r] = g0[150]; pn[r] = g0[300];
      }
    }
    __syncthreads();
#pragma unroll
    for (int r=0;r<3;r++){
      if (tid + r*512 < 1200){
        int row = erow[r], h = eh[r];
        float ghr = gh[row*468 + h];
        float ghz = gh[row*468 + 150 + h];
        float ghn = gh[row*468 + 300 + h];
        float rr = sigm(pr[r] + ghr + bb_r[r]);
        float zz = sigm(pz[r] + ghz + bb_z[r]);
        float nn = tanhf(pn[r] + rr*(ghn + bb_n[r]));
        float h2 = (1.f - zz)*nn + zz*hold[r];
        hold[r] = h2;
        ushort hb = f2bf_rne(h2);
        Ahi[row*168 + h] = hb;
        Alo[row*168 + h] = f2bf_rne(h2 - __uint_as_float(((uint)hb)<<16));
        hs[((size_t)t*N + n0 + row)*G_ + d*H_ + h] = h2;
      }
    }
    __syncthreads();
  }
}

// ---------------------------------------------------------------------------
// GRU scan v4 (sentence, tiny): gi stride GST
// ---------------------------------------------------------------------------
template<int R>
__global__ __launch_bounds__(512,2) void gru_scan_v4(
    const float* __restrict__ gi, const float* __restrict__ Wblk,
    const float* __restrict__ bhh, float* __restrict__ hs,
    int T, int N){
  int d  = blockIdx.y;
  int n0 = blockIdx.x * R;
  __shared__ float hl[2][R][152];
  __shared__ float gh[R][452];
  int tid = threadIdx.x;
  for (int idx = tid; idx < 2*R*152; idx += 512) (&hl[0][0][0])[idx] = 0.f;
  bool jact = tid < 450;
  bool hact = tid < 150;
  float4 Wr[38];
  float bj = 0.f;
  {
    const float4* Wb4 = (const float4*)(Wblk + (size_t)d*38*1800);
    int jj = jact ? tid : 0;
#pragma unroll
    for (int e4 = 0; e4 < 38; ++e4) Wr[e4] = Wb4[e4*450 + jj];
    if (jact) bj = bhh[d*450 + tid];
  }
  float hreg[R];
#pragma unroll
  for (int i=0;i<R;i++) hreg[i] = 0.f;
  int buf = 0;
  __syncthreads();
  for (int step = 0; step < T; ++step){
    int t = d ? (T-1-step) : step;
    const float* gib = gi + ((size_t)t*N + n0)*GST + d*450;
    float pre[R][3];
    if (hact){
#pragma unroll
      for (int i=0;i<R;i++){
        pre[i][0] = gib[(size_t)i*GST + tid];
        pre[i][1] = gib[(size_t)i*GST + 150 + tid];
        pre[i][2] = gib[(size_t)i*GST + 300 + tid];
      }
    }
    if (jact){
      float acc[R];
#pragma unroll
      for (int i=0;i<R;i++) acc[i] = 0.f;
#pragma unroll
      for (int e4 = 0; e4 < 38; ++e4){
        float4 w = Wr[e4];
#pragma unroll
        for (int i=0;i<R;i++){
          float4 hv = *(const float4*)&hl[buf][i][e4*4];
          acc[i] += w.x*hv.x + w.y*hv.y + w.z*hv.z + w.w*hv.w;
        }
      }
#pragma unroll
      for (int i=0;i<R;i++) gh[i][tid] = acc[i] + bj;
    }
    __syncthreads();
    if (hact){
#pragma unroll
      for (int i=0;i<R;i++){
        float r  = sigm(pre[i][0] + gh[i][tid]);
        float z  = sigm(pre[i][1] + gh[i][150+tid]);
        float nn = tanhf(pre[i][2] + r*gh[i][300+tid]);
        float h2 = (1.f - z)*nn + z*hreg[i];
        hreg[i] = h2;
        hl[buf^1][i][tid] = h2;
        hs[((size_t)t*N + n0 + i)*G_ + d*H_ + tid] = h2;
      }
    }
    buf ^= 1;
    __syncthreads();
  }
}

// softmax over t (per n) + weighted sum
__global__ __launch_bounds__(256) void att_combine_kernel(
    const float* __restrict__ score, const float* __restrict__ hs,
    float* __restrict__ out, int T, int N){
  int n = blockIdx.x;
  __shared__ float wa[64];
  if (threadIdx.x < T) wa[threadIdx.x] = score[threadIdx.x*N + n];
  __syncthreads();
  float m = -1e30f;
  for (int t=0;t<T;t++) m = fmaxf(m, wa[t]);
  float den = 0.f;
  for (int t=0;t<T;t++) den += __expf(wa[t]-m);
  float inv = 1.f/den;
  __syncthreads();
  if (threadIdx.x < T) wa[threadIdx.x] = __expf(wa[threadIdx.x]-m)*inv;
  __syncthreads();
  for (int g = threadIdx.x; g < G_; g += 256){
    float acc = 0.f;
    for (int t=0;t<T;t++) acc += wa[t] * hs[((size_t)t*N+n)*G_ + g];
    out[(size_t)n*G_ + g] = acc;
  }
}

// one wave per (b,k): both cosine sims
__global__ __launch_bounds__(256) void cossim_kernel(
    const int* __restrict__ cand, const int* __restrict__ sens,
    const float* __restrict__ ent, const float* __restrict__ sv,
    const float* __restrict__ odoc, float* __restrict__ sim){
  int w = (blockIdx.x*256 + threadIdx.x) >> 6;
  int lane = threadIdx.x & 63;
  if (w >= B_*NC_) return;
  int b = w / NC_, k = w - b*NC_;
  const float* c  = ent + (size_t)cand[b*NC_ + k]*E_;
  const float* a1 = sv  + ((size_t)b*S_ + sens[b])*G_;
  const float* a2 = odoc + (size_t)b*G_;
  float d1=0.f,d2=0.f,cc=0.f,n1=0.f,n2=0.f;
  for (int e = lane; e < E_; e += 64){
    float cv=c[e], v1=a1[e], v2=a2[e];
    d1+=v1*cv; d2+=v2*cv; cc+=cv*cv; n1+=v1*v1; n2+=v2*v2;
  }
  for (int off=32; off; off>>=1){
    d1+=__shfl_xor(d1,off); d2+=__shfl_xor(d2,off); cc+=__shfl_xor(cc,off);
    n1+=__shfl_xor(n1,off); n2+=__shfl_xor(n2,off);
  }
  if (lane == 0){
    float nc = sqrtf(cc);
    sim[(size_t)b*600 + k]       = d1 / fmaxf(sqrtf(n1)*nc, 1e-8f);
    sim[(size_t)b*600 + 300 + k] = d2 / fmaxf(sqrtf(n2)*nc, 1e-8f);
  }
}

// score = sim @ linW^T + linb; gold gather; argmax (first-max tie rule)
__global__ __launch_bounds__(256) void final_kernel(
    const float* __restrict__ sim, const float* __restrict__ linW,
    const float* __restrict__ linb, const int* __restrict__ idx,
    float* __restrict__ out){
  int b = blockIdx.x;
  __shared__ float ss[600];
  __shared__ float sc[300];
  __shared__ float bv[256];
  __shared__ int   bi[256];
  for (int j = threadIdx.x; j < 600; j += 256) ss[j] = sim[(size_t)b*600 + j];
  __syncthreads();
  float bestv = -1e30f; int besti = 0;
  for (int i = threadIdx.x; i < 300; i += 256){
    const float4* wr = (const float4*)(linW + (size_t)i*600);
    float acc = linb[i];
    for (int j4=0; j4<150; j4++){
      float4 w = wr[j4];
      int j = j4*4;
      acc += w.x*ss[j] + w.y*ss[j+1] + w.z*ss[j+2] + w.w*ss[j+3];
    }
    sc[i] = acc;
    out[64 + (size_t)b*300 + i] = acc;
    if (acc > bestv){ bestv = acc; besti = i; }
  }
  bv[threadIdx.x] = bestv; bi[threadIdx.x] = besti;
  __syncthreads();
  for (int s=128; s; s>>=1){
    if (threadIdx.x < s){
      float ov = bv[threadIdx.x+s]; int oi = bi[threadIdx.x+s];
      if (ov > bv[threadIdx.x] || (ov == bv[threadIdx.x] && oi < bi[threadIdx.x])){
        bv[threadIdx.x] = ov; bi[threadIdx.x] = oi;
      }
    }
    __syncthreads();
  }
  if (threadIdx.x == 0){
    out[b] = sc[idx[b]-1];
    out[64 + 64*300 + b] = (float)bi[0];
  }
}

extern "C" void kernel_launch(void* const* d_in, const int* in_sizes, int n_in,
                              void* d_out, int out_size, void* d_ws, size_t ws_size,
                              hipStream_t stream){
  const int*   docs  = (const int*)d_in[0];
  const int*   sens  = (const int*)d_in[1];
  const int*   cand  = (const int*)d_in[2];
  const int*   idx   = (const int*)d_in[3];
  const float* wemb  = (const float*)d_in[4];
  const float* eemb  = (const float*)d_in[5];
  const float* Wih_w = (const float*)d_in[6];
  const float* Whh_w = (const float*)d_in[7];
  const float* bih_w = (const float*)d_in[8];
  const float* bhh_w = (const float*)d_in[9];
  const float* attW_w= (const float*)d_in[10];
  const float* attb_w= (const float*)d_in[11];
  const float* ctx_w = (const float*)d_in[12];
  const float* Wih_s = (const float*)d_in[13];
  const float* Whh_s = (const float*)d_in[14];
  const float* bih_s = (const float*)d_in[15];
  const float* bhh_s = (const float*)d_in[16];
  const float* attW_s= (const float*)d_in[17];
  const float* attb_s= (const float*)d_in[18];
  const float* ctx_s = (const float*)d_in[19];
  const float* linW  = (const float*)d_in[20];
  const float* linb  = (const float*)d_in[21];

  float* ws = (float*)d_ws;
  size_t off = 0;
  float* gi_w    = ws + off; off += (size_t)T_*NW_*GST;   // 188.7 MB (padded)
  float* hs_w    = ws + off; off += (size_t)T_*NW_*G_;    // 59 MB
  float* score_w = ws + off; off += (size_t)T_*NW_;
  float* sv      = ws + off; off += (size_t)NW_*G_;
  float* hs_s    = ws + off; off += (size_t)S_*B_*G_;
  float* score_s = ws + off; off += (size_t)S_*B_;
  float* odoc    = ws + off; off += (size_t)B_*G_;
  float* sim     = ws + off; off += (size_t)B_*600;
  float* Wblk_s  = ws + off; off += (size_t)2*38*450*4;   // sentence Whh tiles
  ushort* Whi    = (ushort*)(ws + off); off += (size_t)912*320/2;
  ushort* Wlo    = (ushort*)(ws + off); off += (size_t)912*320/2;
  ushort* WAhi   = (ushort*)(ws + off); off += (size_t)304*320/2;
  ushort* WAlo   = (ushort*)(ws + off); off += (size_t)304*320/2;
  ushort* WShi   = (ushort*)(ws + off); off += (size_t)304*320/2;
  ushort* WSlo   = (ushort*)(ws + off); off += (size_t)304*320/2;
  ushort* Bsh    = (ushort*)(ws + off); off += (size_t)2*512*160/2;  // gru B hi
  ushort* Bsl    = (ushort*)(ws + off); off += (size_t)2*512*160/2;  // gru B lo
  float* gi_s    = gi_w;   // aliases gi_w: word gi dead before sent_gi runs

  float* out = (float*)d_out;

  // one-time weight preps
  prep_whh_kernel<<<(2*38*450*4+255)/256, 256, 0, stream>>>(Whh_s, Wblk_s);
  prep_whh_mfma<<<(2*512*160+255)/256, 256, 0, stream>>>(Whh_w, Bsh, Bsl);
  split_w_gen<<<912, 128, 0, stream>>>(Wih_w, Whi, Wlo, 900, 300, 320);
  split_w_gen<<<304, 128, 0, stream>>>(attW_w, WAhi, WAlo, 300, 300, 320);
  split_w_gen<<<304, 128, 0, stream>>>(attW_s, WShi, WSlo, 300, 300, 320);

  // word level
  gi_mfma_v5<<<RW_/64, 256, 0, stream>>>(docs, wemb, Whi, Wlo, bih_w, gi_w);
  gru_mfma2<<<dim3(NW_/8, 2), 512, 0, stream>>>(gi_w, Bsh, Bsl, bhh_w,
                                                hs_w, T_, NW_);
  att_mfma_kernel<<<RW_/64, 256, 0, stream>>>(hs_w, WAhi, WAlo, attb_w,
                                              ctx_w, score_w, RW_);
  att_combine_kernel<<<NW_, 256, 0, stream>>>(score_w, hs_w, sv, T_, NW_);

  // sentence level
  sent_gi_kernel<<<RS_/16, 256, 0, stream>>>(sv, Wih_s, bih_s, gi_s);
  gru_scan_v4<2><<<dim3(B_/2, 2), 512, 0, stream>>>(gi_s, Wblk_s, bhh_s,
                                                    hs_s, S_, B_);
  att_mfma_kernel<<<RS_/64, 256, 0, stream>>>(hs_s, WShi, WSlo, attb_s,
                                              ctx_s, score_s, RS_);
  att_combine_kernel<<<B_, 256, 0, stream>>>(score_s, hs_s, odoc, S_, B_);

  // similarity + linear + gold + argmax
  cossim_kernel<<<(B_*NC_*64)/256, 256, 0, stream>>>(cand, sens, eemb, sv, odoc, sim);
  final_kernel<<<B_, 256, 0, stream>>>(sim, linW, linb, idx, out);
}